// Round 5
// baseline (4031.292 us; speedup 1.0000x reference)
//
#include <hip/hip_runtime.h>
#include <hip/hip_bf16.h>

typedef _Float16 f16x8 __attribute__((ext_vector_type(8)));
typedef float f32x4 __attribute__((ext_vector_type(4)));
typedef unsigned int u32;
typedef unsigned long long u64;

// Problem dims
constexpr int kIN = 512;
constexpr int kHID = 1024;
constexpr int kGH = 4096;    // 4*H
constexpr int kT = 512;
constexpr int kB = 32;

// Workspace offsets (bytes)
// xg layout: [t][64 bid][4 g][32 b][16 jj] f16  (4KB per (t,bid) chunk)
constexpr size_t OFF_XG    = 0;            // 134217728
constexpr size_t OFF_XH    = 134217728;    // [16384][512]  f16 = 16777216
constexpr size_t OFF_WXH   = 150994944;    // [4096][512]   f16 = 4194304
constexpr size_t OFF_WHH   = 155189248;    // [4096][1024]  f16 = 8388608
constexpr size_t OFF_BIAS  = 163577856;    // [4096]        f32 = 16384
constexpr size_t OFF_HBUF  = 163594240;    // [2][32][512]  u32 = 131072
constexpr size_t OFF_FLAG  = 163725312;    // [512][64]     u32 = 131072
constexpr size_t WS_NEED   = 163856384;

__device__ __forceinline__ float sigm_f(float x) {
  x = fminf(fmaxf(x, -30.f), 30.f);
  return 1.f / (1.f + __expf(-x));
}
__device__ __forceinline__ float tanh_f(float x) {
  x = fminf(fmaxf(x, -15.f), 15.f);
  float e = __expf(2.f * x);
  return (e - 1.f) / (e + 1.f);
}

// ---------------------------------------------------------------------------
// K0: convert x/Wx/Wh to fp16, bias = bx+bh, zero the per-step flags.
// ---------------------------------------------------------------------------
__global__ void k0_prep(const float* __restrict__ x, const float* __restrict__ Wx,
                        const float* __restrict__ bx, const float* __restrict__ Wh,
                        const float* __restrict__ bh,
                        _Float16* __restrict__ xh, _Float16* __restrict__ wxh,
                        _Float16* __restrict__ whh, float* __restrict__ bias,
                        u32* __restrict__ flags) {
  const long NX = 8388608, NWX = 2097152, NWH = 4194304, NBI = 4096, NFL = 32768;
  const long total = NX + NWX + NWH + NBI + NFL;
  for (long i = (long)blockIdx.x * blockDim.x + threadIdx.x; i < total;
       i += (long)gridDim.x * blockDim.x) {
    long j = i;
    if (j < NX) { xh[j] = (_Float16)x[j]; continue; }
    j -= NX;
    if (j < NWX) { wxh[j] = (_Float16)Wx[j]; continue; }
    j -= NWX;
    if (j < NWH) { whh[j] = (_Float16)Wh[j]; continue; }
    j -= NWH;
    if (j < NBI) { bias[j] = bx[j] + bh[j]; continue; }
    j -= NBI;
    // zero at the coherence point: k2 polls these with agent-scope loads
    __hip_atomic_store(&flags[j], 0u, __ATOMIC_RELAXED, __HIP_MEMORY_SCOPE_AGENT);
  }
}

// ---------------------------------------------------------------------------
// K1: xg = x @ Wx^T + bias, output in k2-friendly layout
// [t][bid(64)][g(4)][b(32)][jj(16)] f16 so k2 reads full 64B lines.
// ---------------------------------------------------------------------------
__global__ __launch_bounds__(256) void k1_xgemm(const _Float16* __restrict__ A,
                                                const _Float16* __restrict__ Bm,
                                                const float* __restrict__ bias,
                                                _Float16* __restrict__ C) {
  __shared__ _Float16 sA[128 * 32];
  __shared__ _Float16 sB[128 * 32];
  const int tid = threadIdx.x;
  const int lane = tid & 63, w = tid >> 6;
  const long m0 = (long)blockIdx.x * 128;
  const long n0 = (long)blockIdx.y * 128;
  const int wm = (w & 1) * 64, wn = (w >> 1) * 64;
  const int fr = lane & 15, fk = (lane >> 4) * 8;

  f32x4 acc[4][4] = {};

  for (int k0 = 0; k0 < kIN; k0 += 32) {
#pragma unroll
    for (int it = 0; it < 2; ++it) {
      int c = it * 256 + tid;
      int row = c >> 2, seg = c & 3;
      *(f16x8*)&sA[c * 8] = *(const f16x8*)&A[(m0 + row) * kIN + k0 + seg * 8];
      *(f16x8*)&sB[c * 8] = *(const f16x8*)&Bm[(n0 + row) * kIN + k0 + seg * 8];
    }
    __syncthreads();
    f16x8 af[4], bf[4];
#pragma unroll
    for (int t = 0; t < 4; ++t) {
      af[t] = *(const f16x8*)&sA[(wm + t * 16 + fr) * 32 + fk];
      bf[t] = *(const f16x8*)&sB[(wn + t * 16 + fr) * 32 + fk];
    }
#pragma unroll
    for (int mt = 0; mt < 4; ++mt)
#pragma unroll
      for (int nt = 0; nt < 4; ++nt)
        acc[mt][nt] = __builtin_amdgcn_mfma_f32_16x16x32_f16(af[mt], bf[nt], acc[mt][nt], 0, 0, 0);
    __syncthreads();
  }

  // Epilogue into transposed layout. col=g*1024+bidx*16+jj, row=b*512+t.
  const int cn = lane & 15, cm4 = (lane >> 4) * 4;
#pragma unroll
  for (int nt = 0; nt < 4; ++nt) {
    long col = n0 + wn + nt * 16 + cn;
    float bv = bias[col];
    long g = col >> 10, bx = (col >> 4) & 63, jj = col & 15;
#pragma unroll
    for (int mt = 0; mt < 4; ++mt)
#pragma unroll
      for (int r = 0; r < 4; ++r) {
        long row = m0 + wm + mt * 16 + cm4 + r;
        long b = row >> 9, tt = row & 511;
        C[(((tt * 64 + bx) * 4 + g) * 32 + b) * 16 + jj] = (_Float16)(acc[mt][nt][r] + bv);
      }
  }
}

// ---------------------------------------------------------------------------
// K2: persistent recurrent kernel. 64 blocks x 256 threads.
// Per step: publish h chunk (sc1 stores) -> vmcnt drain + barrier -> tid0 sets
// per-(step,block) flag (sc1). Consumers: wave0 polls the 64 flags (4 cache
// lines/round), barrier, then ALL waves acquire-fence (buffer_inv) and load
// h_prev with plain CACHED dwordx4 loads (L2-shared per XCD). Poll traffic is
// ~250x smaller than R4's data-polling; data is loaded exactly once per step.
// ---------------------------------------------------------------------------
__global__ __launch_bounds__(256, 1) void k2_rec(const _Float16* __restrict__ xg,
                                                 const _Float16* __restrict__ whh,
                                                 u32* __restrict__ hbuf,
                                                 u32* __restrict__ flags,
                                                 float* __restrict__ out) {
  const int tid = threadIdx.x;
  const int lane = tid & 63, w = tid >> 6;
  const int bid = blockIdx.x;    // 0..63
  const int jb = bid * 16;

  __shared__ float part[4 * 64 * 35];  // [wave][n(64)][m pad 35]

  const int fr = lane & 15;
  const int fq = lane >> 4;

  // Preload B-fragments (Wh slice stays register-resident for the whole scan)
  f16x8 bfr[4][8];
#pragma unroll
  for (int nt = 0; nt < 4; ++nt) {
    long grow = (long)(nt * kHID + jb + fr) * kHID;
#pragma unroll
    for (int kt = 0; kt < 8; ++kt)
      bfr[nt][kt] = *(const f16x8*)&whh[grow + w * 256 + kt * 32 + fq * 8];
  }

  // Elementwise ownership: b = tid>>3 (0..31), jp = tid&7 -> j = jb + jp*2 + {0,1}
  const int eb = tid >> 3;
  const int jp = tid & 7;
  float cst0 = 0.f, cst1 = 0.f;

  const u32* xgu = (const u32*)xg;
  // Prefetch xg for t=0: [t][bid][g][b][jj] -> u32 idx ((t*64+bid)*4+g)*256 + eb*8 + jp
  u32 xn[4];
#pragma unroll
  for (int g = 0; g < 4; ++g)
    xn[g] = xgu[(size_t)((0 * 64 + bid) * 4 + g) * 256 + eb * 8 + jp];

  for (int t = 0; t < kT; ++t) {
    if (t > 0) {
      if (w == 0) {
        // Poll the 64 per-block flags for step t-1 (4 cache lines per round).
        const u32* fl = flags + (size_t)(t - 1) * 64;
        while (true) {
          u32 f = (lane == bid)
                      ? 1u
                      : __hip_atomic_load(&fl[lane], __ATOMIC_RELAXED,
                                          __HIP_MEMORY_SCOPE_AGENT);
          if (__all(f != 0)) break;
        }
      }
      __syncthreads();
      // Acquire: invalidate stale L1/L2 lines so cached h loads see LLC data.
      __builtin_amdgcn_fence(__ATOMIC_ACQUIRE, "agent");
    }

    u32 xv[4];
#pragma unroll
    for (int g = 0; g < 4; ++g) xv[g] = xn[g];
    if (t + 1 < kT) {
#pragma unroll
      for (int g = 0; g < 4; ++g)
        xn[g] = xgu[(size_t)(((t + 1) * 64 + bid) * 4 + g) * 256 + eb * 8 + jp];
    }

    f32x4 acc[2][4] = {};
    if (t > 0) {
      // h_prev A-fragments: plain cached 16B loads (post-inv: fresh from LLC,
      // L2-shareable across the 8 blocks of this XCD).
      const _Float16* hb = (const _Float16*)(hbuf + ((t & 1) ^ 1) * 16384);
#pragma unroll
      for (int kt = 0; kt < 8; ++kt) {
        f16x8 a0 = *(const f16x8*)&hb[(size_t)fr * 1024 + w * 256 + kt * 32 + fq * 8];
        f16x8 a1 = *(const f16x8*)&hb[(size_t)(fr + 16) * 1024 + w * 256 + kt * 32 + fq * 8];
#pragma unroll
        for (int nt = 0; nt < 4; ++nt) {
          acc[0][nt] = __builtin_amdgcn_mfma_f32_16x16x32_f16(a0, bfr[nt][kt], acc[0][nt], 0, 0, 0);
          acc[1][nt] = __builtin_amdgcn_mfma_f32_16x16x32_f16(a1, bfr[nt][kt], acc[1][nt], 0, 0, 0);
        }
      }
    }

    // Store partials: n = nt*16 + fr, m = mt*16 + fq*4 + r
#pragma unroll
    for (int mt = 0; mt < 2; ++mt)
#pragma unroll
      for (int nt = 0; nt < 4; ++nt)
        *(f32x4*)&part[(w * 64 + nt * 16 + fr) * 35 + mt * 16 + fq * 4] = acc[mt][nt];
    __syncthreads();

    // Reduce partials + elementwise LSTM for (eb, jp*2) and (eb, jp*2+1)
    float g0[4], g1[4];
#pragma unroll
    for (int g = 0; g < 4; ++g) {
      union { u32 u; _Float16 h[2]; } xu;
      xu.u = xv[g];
      float s0 = (float)xu.h[0], s1 = (float)xu.h[1];
      int n0 = g * 16 + jp * 2;
#pragma unroll
      for (int wv = 0; wv < 4; ++wv) {
        s0 += part[(wv * 64 + n0) * 35 + eb];
        s1 += part[(wv * 64 + n0 + 1) * 35 + eb];
      }
      g0[g] = s0; g1[g] = s1;
    }

    float h0, h1;
    {
      float ig = sigm_f(g0[0]), fg = sigm_f(g0[1]);
      float gg = tanh_f(g0[2]), og = sigm_f(g0[3]);
      cst0 = cst0 * fg + ig * gg;
      h0 = og * tanh_f(cst0);
    }
    {
      float ig = sigm_f(g1[0]), fg = sigm_f(g1[1]);
      float gg = tanh_f(g1[2]), og = sigm_f(g1[3]);
      cst1 = cst1 * fg + ig * gg;
      h1 = og * tanh_f(cst1);
    }

    // Publish h chunk: write-through sc1 store (1 u32/thread -> 16 lines/block).
    union { u32 u; _Float16 h[2]; } pk;
    pk.h[0] = (_Float16)h0; pk.h[1] = (_Float16)h1;
    __hip_atomic_store(&hbuf[(t & 1) * 16384 + eb * 512 + bid * 8 + jp],
                       pk.u, __ATOMIC_RELAXED, __HIP_MEMORY_SCOPE_AGENT);

    // Drain this wave's publish stores, then barrier (all waves drained; also
    // guards `part` reuse next iteration).
    asm volatile("s_waitcnt vmcnt(0)" ::: "memory");
    __syncthreads();

    if (tid == 0)
      __hip_atomic_store(&flags[(size_t)t * 64 + bid], 1u, __ATOMIC_RELAXED,
                         __HIP_MEMORY_SCOPE_AGENT);

    // out store after the flag: completion off the critical path.
    *(float2*)&out[((long)eb * kT + t) * kHID + jb + jp * 2] = make_float2(h0, h1);
  }
}

// ---------------------------------------------------------------------------
extern "C" void kernel_launch(void* const* d_in, const int* in_sizes, int n_in,
                              void* d_out, int out_size, void* d_ws, size_t ws_size,
                              hipStream_t stream) {
  const float* x  = (const float*)d_in[0];
  const float* Wx = (const float*)d_in[1];
  const float* bx = (const float*)d_in[2];
  const float* Wh = (const float*)d_in[3];
  const float* bh = (const float*)d_in[4];
  float* out = (float*)d_out;

  if (ws_size < WS_NEED) return;

  char* ws = (char*)d_ws;
  _Float16* xg    = (_Float16*)(ws + OFF_XG);
  _Float16* xh    = (_Float16*)(ws + OFF_XH);
  _Float16* wxh   = (_Float16*)(ws + OFF_WXH);
  _Float16* whh   = (_Float16*)(ws + OFF_WHH);
  float*    bias  = (float*)(ws + OFF_BIAS);
  u32*      hbuf  = (u32*)(ws + OFF_HBUF);
  u32*      flags = (u32*)(ws + OFF_FLAG);

  hipLaunchKernelGGL(k0_prep, dim3(4096), dim3(256), 0, stream,
                     x, Wx, bx, Wh, bh, xh, wxh, whh, bias, flags);
  hipLaunchKernelGGL(k1_xgemm, dim3(128, 32), dim3(256), 0, stream,
                     xh, wxh, bias, xg);
  hipLaunchKernelGGL(k2_rec, dim3(64), dim3(256), 0, stream,
                     xg, whh, hbuf, flags, out);
}